// Round 9
// baseline (486.748 us; speedup 1.0000x reference)
//
#include <hip/hip_runtime.h>
#include <math.h>

typedef float  f4v __attribute__((ext_vector_type(4)));
typedef short  s8v __attribute__((ext_vector_type(8)));
typedef int    i4v __attribute__((ext_vector_type(4)));

__device__ __forceinline__ float sigm(float x) { return 1.f / (1.f + expf(-x)); }
__device__ __forceinline__ unsigned short f2bf(float f) {
    unsigned int u = __float_as_uint(f);
    return (unsigned short)((u + 0x7FFF + ((u >> 16) & 1)) >> 16);   // RTNE
}
// packed f32x2 -> bf16x2 in ONE VALU op (lo = first arg)
__device__ __forceinline__ unsigned int cvt2(float lo, float hi) {
    unsigned int r;
    asm("v_cvt_pk_bf16_f32 %0, %1, %2" : "=v"(r) : "v"(lo), "v"(hi));
    return r;
}
__device__ __forceinline__ s8v pack8(float4 a, float4 b) {
    union { unsigned int u[4]; s8v v; } r;
    r.u[0] = cvt2(a.x, a.y); r.u[1] = cvt2(a.z, a.w);
    r.u[2] = cvt2(b.x, b.y); r.u[3] = cvt2(b.z, b.w);
    return r.v;
}
// async global->LDS DMA, 16 B per lane; dest must be linear (base + lane*16)
__device__ __forceinline__ void gload16(const void* g, void* l) {
    __builtin_amdgcn_global_load_lds((const __attribute__((address_space(1))) void*)g,
                                     (__attribute__((address_space(3))) void*)l, 16, 0, 0);
}

// ---------------- amax over Whh (for i8 quantization scale) ----------------
__global__ __launch_bounds__(256) void k_amax(const float* __restrict__ Whh,
                                              unsigned int* __restrict__ amax_bits) {
    int i = blockIdx.x * 256 + threadIdx.x;          // grid 1024 -> 262144
    float v = fabsf(Whh[i]);
#pragma unroll
    for (int o = 1; o < 64; o <<= 1) v = fmaxf(v, __shfl_xor(v, o));
    if ((threadIdx.x & 63) == 0) atomicMax(amax_bits, __float_as_uint(v));
}

// ---------------- prep: pack weights ----------------
// W2p: [64co][k=(ky*4+kx)*32+ci]   (tap-major K, 32768 ush)
// W3p: [64co][k=(ky*3+kx)*64+ci]   (tap-major K, K=576, 36864 ush)
__global__ __launch_bounds__(256) void k_prep(const float* __restrict__ W2, const float* __restrict__ W3,
                                              const float* __restrict__ Wfc, const float* __restrict__ Wih,
                                              const float* __restrict__ W1, const float* __restrict__ Whh,
                                              const unsigned int* __restrict__ amax_bits,
                                              unsigned short* __restrict__ W2p, unsigned short* __restrict__ W3p,
                                              unsigned short* __restrict__ Wfcp, unsigned short* __restrict__ Wihp,
                                              unsigned short* __restrict__ W1p, signed char* __restrict__ Wq) {
    int i = blockIdx.x * 256 + threadIdx.x;
    if (i < 32768) {
        int co = i >> 9, k = i & 511, t = k >> 5, ci = k & 31, ky = t >> 2, kx = t & 3;
        W2p[i] = f2bf(W2[co * 512 + ci * 16 + ky * 4 + kx]);
    } else if (i < 69632) {
        int j = i - 32768;
        int co = j / 576, k = j - co * 576, t = k >> 6, ci = k & 63;
        int ky = t / 3, kx = t - ky * 3;
        W3p[j] = f2bf(W3[((co * 64 + ci) * 3 + ky) * 3 + kx]);
    } else if (i < 1675264) {
        int j = i - 69632;
        Wfcp[j] = f2bf(Wfc[j]);
    } else if (i < 2199552) {
        int j = i - 1675264;
        int n = j >> 9, k = j & 511;
        Wihp[j] = f2bf(Wih[n * 517 + k]);
    } else if (i < 2205696) {
        int j = i - 2199552;
        W1p[j] = f2bf(W1[j] * (1.f / 255.f));
    } else if (i < 2467840) {
        int j = i - 2205696;
        float amax = __uint_as_float(amax_bits[0]);
        float s = 127.f / amax;
        int qv = (int)rintf(Whh[j] * s);
        qv = qv > 127 ? 127 : (qv < -127 ? -127 : qv);
        Wq[j] = (signed char)qv;                     // [1024][256] natural
    }
}

// ---------------- conv1: DMA-staged fp32 half-image, grid 2048 x 256 thr (R7 best) ------
__global__ __launch_bounds__(256, 3) void k_conv1(const float* __restrict__ img,
                                                  const unsigned short* __restrict__ Bw,
                                                  const float* __restrict__ bias,
                                                  unsigned short* __restrict__ out) {
    __shared__ float sF[12096];                      // 48,384 B (max: 3*48*84 fp32)
    int tid = threadIdx.x;
    int lane = tid & 63, w = tid >> 6;               // 4 waves
    int l15 = lane & 15, q = lane >> 4;
    int bh = blockIdx.x & 1;
    int im = blockIdx.x >> 1;
    const int y0    = bh ? 40 : 0;                   // staged rows [y0, y0+ny)
    const int S     = bh ? 14784 : 16128;            // bytes per channel span (ny*336)
    const int fullc = bh ? 14 : 15;                  // full 1KB DMA chunks per channel
    const int tailg = bh ? 28 : 48;                  // 16B tail granules per channel
    const int t0    = bh ? 13 : 0;                   // first M-tile
    const int nt    = bh ? 12 : 13;                  // tiles in this block
    char* sFb = (char*)sF;
    const char* gimg = (const char*)(img + (size_t)im * 21168);
    // ---- stage: per channel, full 1KB wave-chunks via DMA; tail via registers ----
    for (int c = 0; c < 3; ++c) {
        const char* gb = gimg + c * 28224 + y0 * 336;
        char* lb = sFb + c * S;
        for (int j = w; j < fullc; j += 4) {
            int off = j * 1024 + lane * 16;
            gload16(gb + off, lb + off);
        }
        if (w == c && lane < tailg) {
            int off = fullc * 1024 + lane * 16;
            *(float4*)(lb + off) = *(const float4*)(gb + off);
        }
    }
    // ---- B fragments (L2-hot) + per-(ks,q) channel/row offsets ----
    const unsigned short* Bp0 = Bw + l15 * 192 + q * 8;
    const unsigned short* Bp1 = Bw + (16 + l15) * 192 + q * 8;
    s8v bf0[6], bf1[6];
#pragma unroll
    for (int ks = 0; ks < 6; ++ks) {
        bf0[ks] = *(const s8v*)(Bp0 + ks * 32);
        bf1[ks] = *(const s8v*)(Bp1 + ks * 32);
    }
    int koff[6];
#pragma unroll
    for (int ks = 0; ks < 6; ++ks) {
        int kq = ks * 4 + q;                         // k0/8
        int c = kq >> 3, ky = kq & 7;
        koff[ks] = c * S + ky * 336;
    }
    __syncthreads();                                 // drains DMA (vmcnt 0) + tail writes
    // ---- compute: wave w owns local tiles {w, w+4, w+8, w+12} ∩ [0,nt) ----
    f4v acc[4][2];
#pragma unroll
    for (int i = 0; i < 4; ++i) { acc[i][0] = (f4v){0.f,0.f,0.f,0.f}; acc[i][1] = (f4v){0.f,0.f,0.f,0.f}; }
#pragma unroll
    for (int tt = 0; tt < 4; ++tt) {
        int li = w + tt * 4;
        if (li < nt) {
            int p = (t0 + li) * 16 + l15;            // pixel index, < 400
            int oy = p / 20, ox = p - oy * 20;
            int tb = (oy * 4 - y0) * 336 + ox * 16;
#pragma unroll
            for (int ks = 0; ks < 6; ++ks) {
                float4 a0 = *(const float4*)(sFb + koff[ks] + tb);
                float4 a1 = *(const float4*)(sFb + koff[ks] + tb + 16);
                s8v ua = pack8(a0, a1);
                acc[tt][0] = __builtin_amdgcn_mfma_f32_16x16x32_bf16(ua, bf0[ks], acc[tt][0], 0, 0, 0);
                acc[tt][1] = __builtin_amdgcn_mfma_f32_16x16x32_bf16(ua, bf1[ks], acc[tt][1], 0, 0, 0);
            }
        }
    }
    __syncthreads();                                 // all image reads done -> alias LDS
    // ---- epilogue: bias+relu+pack into aliased LDS [32 n][212] shorts ----
    unsigned short* cS = (unsigned short*)sFb;
    float b0v = bias[l15], b1v = bias[16 + l15];
#pragma unroll
    for (int tt = 0; tt < 4; ++tt) {
        int li = w + tt * 4;
        if (li < nt) {
            int pc = li * 16 + q * 4;
#pragma unroll
            for (int r = 0; r < 4; r += 2) {
                float v0 = acc[tt][0][r] + b0v;     v0 = v0 > 0.f ? v0 : 0.f;
                float v1 = acc[tt][0][r + 1] + b0v; v1 = v1 > 0.f ? v1 : 0.f;
                *(unsigned int*)&cS[l15 * 212 + pc + r] = cvt2(v0, v1);
                float u0 = acc[tt][1][r] + b1v;     u0 = u0 > 0.f ? u0 : 0.f;
                float u1 = acc[tt][1][r + 1] + b1v; u1 = u1 > 0.f ? u1 : 0.f;
                *(unsigned int*)&cS[(16 + l15) * 212 + pc + r] = cvt2(u0, u1);
            }
        }
    }
    __syncthreads();
    // ---- coalesced store: out[(im*32+n)*400 + t0*16 + p_local] ----
    int hc = nt * 8;                                 // u32 per output row
    const unsigned int* cw = (const unsigned int*)cS;
    for (int n = w; n < 32; n += 4) {
        const unsigned int* crow = cw + n * 106;
        unsigned int* orow = (unsigned int*)(out + (im * 32 + n) * 400 + t0 * 16);
        for (int j = lane; j < hc; j += 64) orow[j] = crow[j];
    }
}

// ---------------- conv2: LDS-staged implicit GEMM, 2 images/block, grid 512 (R7) --------
__global__ __launch_bounds__(256, 2) void k_conv2(const unsigned short* __restrict__ A,
                                                  const unsigned short* __restrict__ Bw,
                                                  const float* __restrict__ bias,
                                                  unsigned short* __restrict__ out) {
    __shared__ unsigned short sA[800 * 32];    // 51200 B
    __shared__ unsigned short c2s[64][196];    // 25088 B
    int tid = threadIdx.x;
    int lane = tid & 63, w = tid >> 6;
    int l15 = lane & 15, q = lane >> 4;
    int img0 = blockIdx.x * 2;
    char* sAb = (char*)sA;
    const s8v* srcv = (const s8v*)(A + img0 * 12800);
    for (int wi = tid; wi < 3200; wi += 256) {
        s8v v = srcv[wi];
        int f = wi * 8;
        int im = f / 12800, r = f - im * 12800, ci = r / 400, p = r - ci * 400;
#pragma unroll
        for (int j = 0; j < 8; ++j) {
            int R = im * 400 + p + j;
            int Rl = (R >> 1) + (R & 1) * 400;
            int by = (Rl * 32 + ci) * 2 ^ ((Rl & 7) << 4);
            *(unsigned short*)(sAb + by) = (unsigned short)v[j];
        }
    }
    __syncthreads();
    int Rb[3];
#pragma unroll
    for (int mf = 0; mf < 3; ++mf) {
        int t = w * 3 + mf;
        int im = t / 6;
        int pp = (t - im * 6) * 16 + l15;
        int px = pp > 80 ? 80 : pp;
        int oy = px / 9, ox = px - oy * 9;
        Rb[mf] = im * 400 + oy * 40 + ox * 2;
    }
    const unsigned short* Bp0 = Bw + l15 * 512 + q * 8;
    const unsigned short* Bp1 = Bw + (16 + l15) * 512 + q * 8;
    const unsigned short* Bp2 = Bw + (32 + l15) * 512 + q * 8;
    const unsigned short* Bp3 = Bw + (48 + l15) * 512 + q * 8;
    f4v acc[3][4];
#pragma unroll
    for (int i = 0; i < 3; ++i)
#pragma unroll
        for (int j = 0; j < 4; ++j) acc[i][j] = (f4v){0.f, 0.f, 0.f, 0.f};
#pragma unroll
    for (int s = 0; s < 16; ++s) {
        const int ky = s >> 2, kx = s & 3;
        const int d = ky * 20 + kx;
        s8v a[3];
#pragma unroll
        for (int mf = 0; mf < 3; ++mf) {
            int R = Rb[mf] + d;
            int Rl = (R >> 1) + (R & 1) * 400;
            int by = (Rl * 64 + q * 16) ^ ((Rl & 7) << 4);
            a[mf] = *(const s8v*)(sAb + by);
        }
        s8v b0 = *(const s8v*)(Bp0 + s * 32);
        s8v b1 = *(const s8v*)(Bp1 + s * 32);
        s8v b2 = *(const s8v*)(Bp2 + s * 32);
        s8v b3 = *(const s8v*)(Bp3 + s * 32);
#pragma unroll
        for (int mf = 0; mf < 3; ++mf) {
            acc[mf][0] = __builtin_amdgcn_mfma_f32_16x16x32_bf16(a[mf], b0, acc[mf][0], 0, 0, 0);
            acc[mf][1] = __builtin_amdgcn_mfma_f32_16x16x32_bf16(a[mf], b1, acc[mf][1], 0, 0, 0);
            acc[mf][2] = __builtin_amdgcn_mfma_f32_16x16x32_bf16(a[mf], b2, acc[mf][2], 0, 0, 0);
            acc[mf][3] = __builtin_amdgcn_mfma_f32_16x16x32_bf16(a[mf], b3, acc[mf][3], 0, 0, 0);
        }
    }
#pragma unroll
    for (int nf = 0; nf < 4; ++nf) {
        int co = nf * 16 + l15;
        float b = bias[co];
#pragma unroll
        for (int mf = 0; mf < 3; ++mf) {
            int rr = (w * 3 + mf) * 16 + q * 4;
#pragma unroll
            for (int r = 0; r < 4; r += 2) {
                float v0 = acc[mf][nf][r] + b;     v0 = v0 > 0.f ? v0 : 0.f;
                float v1 = acc[mf][nf][r + 1] + b; v1 = v1 > 0.f ? v1 : 0.f;
                *(unsigned int*)&c2s[co][rr + r] = cvt2(v0, v1);
            }
        }
    }
    __syncthreads();
    for (int idx = tid; idx < 10368; idx += 256) {
        int im = idx / 5184, r2 = idx - im * 5184, co = r2 / 81, p = r2 - co * 81;
        out[(img0 + im) * 5184 + r2] = c2s[co][im * 96 + p];
    }
}

// ---------------- conv3: LDS-staged implicit GEMM, 2 images/block, grid 512 (R7) --------
__global__ __launch_bounds__(256, 2) void k_conv3(const unsigned short* __restrict__ A,
                                                  const unsigned short* __restrict__ Bw,
                                                  const float* __restrict__ bias,
                                                  unsigned short* __restrict__ out) {
    __shared__ unsigned short sA[162 * 64];    // 20736 B
    __shared__ unsigned short c3s[64][132];    // 16896 B
    int tid = threadIdx.x;
    int lane = tid & 63, w = tid >> 6;
    int l15 = lane & 15, q = lane >> 4;
    int img0 = blockIdx.x * 2;
    char* sAb = (char*)sA;
    const s8v* srcv = (const s8v*)(A + img0 * 5184);
    for (int wi = tid; wi < 1296; wi += 256) {
        s8v v = srcv[wi];
        int f = wi * 8;
#pragma unroll
        for (int j = 0; j < 8; ++j) {
            int fe = f + j;
            int im = fe / 5184, r = fe - im * 5184, ci = r / 81, p = r - ci * 81;
            int R = im * 81 + p;
            int by = (R * 64 + ci) * 2 ^ ((R & 7) << 4);
            *(unsigned short*)(sAb + by) = (unsigned short)v[j];
        }
    }
    __syncthreads();
    int Rb[2];
#pragma unroll
    for (int mf = 0; mf < 2; ++mf) {
        int t = w * 2 + mf;
        int im = t >> 2;
        int pp = (t & 3) * 16 + l15;
        int px = pp > 48 ? 48 : pp;
        int oy = px / 7, ox = px - oy * 7;
        Rb[mf] = im * 81 + oy * 9 + ox;
    }
    const unsigned short* Bp0 = Bw + l15 * 576 + q * 8;
    const unsigned short* Bp1 = Bw + (16 + l15) * 576 + q * 8;
    const unsigned short* Bp2 = Bw + (32 + l15) * 576 + q * 8;
    const unsigned short* Bp3 = Bw + (48 + l15) * 576 + q * 8;
    f4v acc[2][4];
#pragma unroll
    for (int i = 0; i < 2; ++i)
#pragma unroll
        for (int j = 0; j < 4; ++j) acc[i][j] = (f4v){0.f, 0.f, 0.f, 0.f};
#pragma unroll
    for (int s = 0; s < 18; ++s) {
        const int tap = s >> 1, cb2 = (s & 1) * 64;
        const int ky = tap / 3, kx = tap - ky * 3;
        const int d = ky * 9 + kx;
        s8v a0, a1;
        {
            int R = Rb[0] + d;
            int by = (R * 128 + cb2 + q * 16) ^ ((R & 7) << 4);
            a0 = *(const s8v*)(sAb + by);
        }
        {
            int R = Rb[1] + d;
            int by = (R * 128 + cb2 + q * 16) ^ ((R & 7) << 4);
            a1 = *(const s8v*)(sAb + by);
        }
        s8v b0 = *(const s8v*)(Bp0 + s * 32);
        s8v b1 = *(const s8v*)(Bp1 + s * 32);
        s8v b2 = *(const s8v*)(Bp2 + s * 32);
        s8v b3 = *(const s8v*)(Bp3 + s * 32);
        acc[0][0] = __builtin_amdgcn_mfma_f32_16x16x32_bf16(a0, b0, acc[0][0], 0, 0, 0);
        acc[0][1] = __builtin_amdgcn_mfma_f32_16x16x32_bf16(a0, b1, acc[0][1], 0, 0, 0);
        acc[0][2] = __builtin_amdgcn_mfma_f32_16x16x32_bf16(a0, b2, acc[0][2], 0, 0, 0);
        acc[0][3] = __builtin_amdgcn_mfma_f32_16x16x32_bf16(a0, b3, acc[0][3], 0, 0, 0);
        acc[1][0] = __builtin_amdgcn_mfma_f32_16x16x32_bf16(a1, b0, acc[1][0], 0, 0, 0);
        acc[1][1] = __builtin_amdgcn_mfma_f32_16x16x32_bf16(a1, b1, acc[1][1], 0, 0, 0);
        acc[1][2] = __builtin_amdgcn_mfma_f32_16x16x32_bf16(a1, b2, acc[1][2], 0, 0, 0);
        acc[1][3] = __builtin_amdgcn_mfma_f32_16x16x32_bf16(a1, b3, acc[1][3], 0, 0, 0);
    }
#pragma unroll
    for (int nf = 0; nf < 4; ++nf) {
        int co = nf * 16 + l15;
        float b = bias[co];
#pragma unroll
        for (int mf = 0; mf < 2; ++mf) {
            int rr = (w * 2 + mf) * 16 + q * 4;
#pragma unroll
            for (int r = 0; r < 4; r += 2) {
                float v0 = acc[mf][nf][r] + b;     v0 = v0 > 0.f ? v0 : 0.f;
                float v1 = acc[mf][nf][r + 1] + b; v1 = v1 > 0.f ? v1 : 0.f;
                *(unsigned int*)&c3s[co][rr + r] = cvt2(v0, v1);
            }
        }
    }
    __syncthreads();
    for (int idx = tid; idx < 6272; idx += 256) {
        int im = idx / 3136, r2 = idx - im * 3136, co = r2 / 49, p = r2 - co * 49;
        out[(img0 + im) * 3136 + r2] = c3s[co][im * 64 + p];
    }
}

// ---------------- FC: LDS-staged GEMM, 32x64 tile, 512 thr, grid (32,8) ----------------
__global__ __launch_bounds__(512) void k_fc(const unsigned short* __restrict__ A,
                                            const unsigned short* __restrict__ Bw,
                                            const float* __restrict__ bias,
                                            unsigned short* __restrict__ out) {
    __shared__ unsigned short sA[32 * 128];          // 8 KB
    __shared__ unsigned short sB[64 * 128];          // 16 KB
    int tid = threadIdx.x;
    int lane = tid & 63, w = tid >> 6;               // 8 waves
    int l15 = lane & 15, q = lane >> 4;
    int m0 = blockIdx.x * 32, n0 = blockIdx.y * 64;
    int mh = w & 1, nh = w >> 1;                     // wave -> (m-half, n-quarter)
    char* sAb = (char*)sA; char* sBb = (char*)sB;
    int ar = mh * 16 + l15;                          // A fragment row
    int br = nh * 16 + l15;                          // B fragment row
    f4v acc = (f4v){0.f, 0.f, 0.f, 0.f};
    for (int ks = 0; ks < 25; ++ks) {
        int kb = ks * 128;
        if (ks < 24) {
            {   // A: 512 granules (32 rows x 16), one per thread
                int row = tid >> 4, kg = tid & 15;
                s8v v = *(const s8v*)(A + (m0 + row) * 3136 + kb + kg * 8);
                int by = (row * 256 + kg * 16) ^ ((row & 7) << 4);
                *(s8v*)(sAb + by) = v;
            }
#pragma unroll
            for (int h = 0; h < 2; ++h) {            // B: 1024 granules (64 rows x 16)
                int g = tid + h * 512;
                int row = g >> 4, kg = g & 15;
                s8v v = *(const s8v*)(Bw + (n0 + row) * 3136 + kb + kg * 8);
                int by = (row * 256 + kg * 16) ^ ((row & 7) << 4);
                *(s8v*)(sBb + by) = v;
            }
        } else {                                     // tail: bk = 64
            if (tid < 256) {
                int row = tid >> 3, kg = tid & 7;
                s8v v = *(const s8v*)(A + (m0 + row) * 3136 + kb + kg * 8);
                int by = (row * 256 + kg * 16) ^ ((row & 7) << 4);
                *(s8v*)(sAb + by) = v;
            }
            {
                int row = tid >> 3, kg = tid & 7;    // 512 thr -> 64 rows x 8
                s8v v = *(const s8v*)(Bw + (n0 + row) * 3136 + kb + kg * 8);
                int by = (row * 256 + kg * 16) ^ ((row & 7) << 4);
                *(s8v*)(sBb + by) = v;
            }
        }
        __syncthreads();
        int nkc = (ks < 24) ? 4 : 2;
        for (int kc = 0; kc < nkc; ++kc) {
            int abz = (ar * 256 + kc * 64 + q * 16) ^ ((ar & 7) << 4);
            int bbz = (br * 256 + kc * 64 + q * 16) ^ ((br & 7) << 4);
            s8v av = *(const s8v*)(sAb + abz);
            s8v bv = *(const s8v*)(sBb + bbz);
            acc = __builtin_amdgcn_mfma_f32_16x16x32_bf16(av, bv, acc, 0, 0, 0);
        }
        __syncthreads();
    }
    int n = n0 + nh * 16 + l15;
    float bi = bias[n];
#pragma unroll
    for (int r = 0; r < 4; ++r) {
        int m = m0 + mh * 16 + q * 4 + r;
        float v = acc[r] + bi; v = v > 0.f ? v : 0.f;
        out[m * 512 + n] = f2bf(v);
    }
}

// ---------------- gx: LDS-staged GEMM, 32x64 tile, 512 thr, grid (32,16) ----------------
__global__ __launch_bounds__(512) void k_gx(const unsigned short* __restrict__ A,
                                            const unsigned short* __restrict__ Bw,
                                            const float* __restrict__ Wih,
                                            const float* __restrict__ bih,
                                            const float* __restrict__ bhh,
                                            const int* __restrict__ act,
                                            float* __restrict__ out) {
    __shared__ unsigned short sA[32 * 128];          // 8 KB
    __shared__ unsigned short sB[64 * 128];          // 16 KB
    int tid = threadIdx.x;
    int lane = tid & 63, w = tid >> 6;
    int l15 = lane & 15, q = lane >> 4;
    int m0 = blockIdx.x * 32, n0 = blockIdx.y * 64;
    int mh = w & 1, nh = w >> 1;
    char* sAb = (char*)sA; char* sBb = (char*)sB;
    int ar = mh * 16 + l15;
    int br = nh * 16 + l15;
    f4v acc = (f4v){0.f, 0.f, 0.f, 0.f};
#pragma unroll
    for (int ks = 0; ks < 4; ++ks) {
        int kb = ks * 128;
        {
            int row = tid >> 4, kg = tid & 15;
            s8v v = *(const s8v*)(A + (m0 + row) * 512 + kb + kg * 8);
            int by = (row * 256 + kg * 16) ^ ((row & 7) << 4);
            *(s8v*)(sAb + by) = v;
        }
#pragma unroll
        for (int h = 0; h < 2; ++h) {
            int g = tid + h * 512;
            int row = g >> 4, kg = g & 15;
            s8v v = *(const s8v*)(Bw + (n0 + row) * 512 + kb + kg * 8);
            int by = (row * 256 + kg * 16) ^ ((row & 7) << 4);
            *(s8v*)(sBb + by) = v;
        }
        __syncthreads();
#pragma unroll
        for (int kc = 0; kc < 4; ++kc) {
            int abz = (ar * 256 + kc * 64 + q * 16) ^ ((ar & 7) << 4);
            int bbz = (br * 256 + kc * 64 + q * 16) ^ ((br & 7) << 4);
            s8v av = *(const s8v*)(sAb + abz);
            s8v bv = *(const s8v*)(sBb + bbz);
            acc = __builtin_amdgcn_mfma_f32_16x16x32_bf16(av, bv, acc, 0, 0, 0);
        }
        __syncthreads();
    }
    int n = n0 + nh * 16 + l15;
    float cbias = bih[n] + bhh[n];
#pragma unroll
    for (int r = 0; r < 4; ++r) {
        int m = m0 + mh * 16 + q * 4 + r;
        int a = act[m];
        out[m * 1024 + n] = acc[r] + Wih[n * 517 + 512 + a] + cbias;
    }
}

// ---------------- fused LSTM + heads: 32 wgs x 1 env; h history kept in LDS --------------
// After the 32-step recurrence, each block computes its own env's policy/value heads for
// all 32 timesteps (wave w handles t = 2w, 2w+1; h rows broadcast-read from LDS) and
// writes hT/cT directly. Kills k_heads' launch + the hs/cb global round-trip.
__global__ __launch_bounds__(1024) void k_lstm_all(const float* __restrict__ h0,
                                                   const float* __restrict__ c0,
                                                   const float* __restrict__ done,
                                                   const float* __restrict__ gx,
                                                   const signed char* __restrict__ Wq,
                                                   const unsigned int* __restrict__ amax_bits,
                                                   const float* __restrict__ Wp1, const float* __restrict__ bp1,
                                                   const float* __restrict__ Wp2, const float* __restrict__ bp2,
                                                   const float* __restrict__ Wv1, const float* __restrict__ bv1,
                                                   const float* __restrict__ Wv2, const float* __restrict__ bv2,
                                                   float* __restrict__ out) {
    int b = blockIdx.x;
    int tid = threadIdx.x;
    int w = tid >> 6, lane = tid & 63;
    int l15 = lane & 15, q = lane >> 4;
    __shared__ float gbuf[1024];
    __shared__ float cst[256];
    __shared__ signed char hA[4][64][16];            // A-operand layout, only m=0 rows live
    __shared__ float hsb[32][256];                   // full h history (32 KB)

    i4v wfr[4][4];
    const signed char* wb = Wq + (w * 64 + l15) * 256 + q * 16;
#pragma unroll
    for (int s = 0; s < 4; ++s)
#pragma unroll
        for (int kf = 0; kf < 4; ++kf)
            wfr[s][kf] = *(const i4v*)(wb + s * 16 * 256 + kf * 64);
    float sw = __uint_as_float(amax_bits[0]) * (1.f / (127.f * 127.f));

    ((int*)hA)[tid] = 0;                             // zero all (dead rows stay 0)
    __syncthreads();
    if (tid < 256) {
        int u = tid;
        cst[u] = c0[b * 256 + u];
        float m0v = 1.f - done[b];
        float hv = h0[b * 256 + u] * m0v;
        hv = hv > 1.f ? 1.f : (hv < -1.f ? -1.f : hv);
        hA[u >> 6][((u >> 4) & 3) * 16][u & 15] = (signed char)(int)rintf(hv * 127.f);
    }
    __syncthreads();

    for (int t = 0; t < 32; ++t) {
        float gxi = 0.f, gxf = 0.f, gxg = 0.f, gxo = 0.f, dcur = 0.f, dnxt = 0.f;
        if (tid < 256) {
            const float* gr = gx + (t * 32 + b) * 1024;
            gxi = gr[tid]; gxf = gr[256 + tid]; gxg = gr[512 + tid]; gxo = gr[768 + tid];
            dcur = done[t * 32 + b];
            dnxt = (t < 31) ? done[(t + 1) * 32 + b] : 1.f;
        }
        i4v acc[4];
#pragma unroll
        for (int s = 0; s < 4; ++s) acc[s] = (i4v){0, 0, 0, 0};
#pragma unroll
        for (int kf = 0; kf < 4; ++kf) {
            i4v a = *(const i4v*)&hA[kf][lane][0];
#pragma unroll
            for (int s = 0; s < 4; ++s)
                acc[s] = __builtin_amdgcn_mfma_i32_16x16x64_i8(a, wfr[s][kf], acc[s], 0, 0, 0);
        }
        if (q == 0) {                                // row 0 of C lives in reg 0 of lanes 0..15
#pragma unroll
            for (int s = 0; s < 4; ++s)
                gbuf[w * 64 + s * 16 + l15] = (float)acc[s][0];
        }
        __syncthreads();
        if (tid < 256) {
            int u = tid;
            float gi = gbuf[u] * sw + gxi;
            float gf = gbuf[256 + u] * sw + gxf;
            float gg = gbuf[512 + u] * sw + gxg;
            float go = gbuf[768 + u] * sw + gxo;
            float cm = cst[u] * (1.f - dcur);
            float cn = sigm(gf) * cm + sigm(gi) * tanhf(gg);
            float hn = sigm(go) * tanhf(cn);
            cst[u] = cn;
            hsb[t][u] = hn;
            float hv = hn * (1.f - dnxt);            // |h|<1; done in {0,1} -> exact
            hA[u >> 6][((u >> 4) & 3) * 16][u & 15] = (signed char)(int)rintf(hv * 127.f);
        }
        __syncthreads();
    }

    // ---- heads: wave w -> timesteps 2w, 2w+1 (h rows broadcast from LDS) ----
#pragma unroll
    for (int th = 0; th < 2; ++th) {
        int t = w * 2 + th;
        int m = t * 32 + b;
        const float4* hv = (const float4*)&hsb[t][0];
        const float4* wp = (const float4*)(Wp1 + lane * 256);
        const float4* wq = (const float4*)(Wv1 + lane * 256);
        float ap = 0.f, av = 0.f;
#pragma unroll 8
        for (int k = 0; k < 64; ++k) {
            float4 h4 = hv[k];
            float4 p4 = wp[k];
            float4 q4 = wq[k];
            ap += h4.x * p4.x + h4.y * p4.y + h4.z * p4.z + h4.w * p4.w;
            av += h4.x * q4.x + h4.y * q4.y + h4.z * q4.z + h4.w * q4.w;
        }
        float hp = tanhf(ap + bp1[lane]);
        float hq = tanhf(av + bv1[lane]);
#pragma unroll
        for (int j = 0; j < 5; ++j) {
            float s = hp * Wp2[j * 64 + lane];
            s += __shfl_xor(s, 1); s += __shfl_xor(s, 2); s += __shfl_xor(s, 4);
            s += __shfl_xor(s, 8); s += __shfl_xor(s, 16); s += __shfl_xor(s, 32);
            if (lane == 0) out[m * 5 + j] = s + bp2[j];
        }
        float s = hq * Wv2[lane];
        s += __shfl_xor(s, 1); s += __shfl_xor(s, 2); s += __shfl_xor(s, 4);
        s += __shfl_xor(s, 8); s += __shfl_xor(s, 16); s += __shfl_xor(s, 32);
        if (lane == 0) out[5120 + m] = s + bv2[0];
    }
    if (tid < 256) {
        out[6144 + b * 256 + tid] = hsb[31][tid];    // hT
        out[6144 + 8192 + b * 256 + tid] = cst[tid]; // cT
    }
}

extern "C" void kernel_launch(void* const* d_in, const int* in_sizes, int n_in,
                              void* d_out, int out_size, void* d_ws, size_t ws_size,
                              hipStream_t stream) {
    const float* image = (const float*)d_in[0];
    const int*   act   = (const int*)d_in[1];
    const float* done  = (const float*)d_in[2];
    const float* h0    = (const float*)d_in[3];
    const float* c0    = (const float*)d_in[4];
    const float* W1    = (const float*)d_in[5];
    const float* b1    = (const float*)d_in[6];
    const float* W2    = (const float*)d_in[7];
    const float* b2    = (const float*)d_in[8];
    const float* W3    = (const float*)d_in[9];
    const float* b3    = (const float*)d_in[10];
    const float* Wfc   = (const float*)d_in[11];
    const float* bfc   = (const float*)d_in[12];
    const float* Wih   = (const float*)d_in[13];
    const float* Whh   = (const float*)d_in[14];
    const float* bih   = (const float*)d_in[15];
    const float* bhh   = (const float*)d_in[16];
    const float* Wp1   = (const float*)d_in[17];
    const float* bp1   = (const float*)d_in[18];
    const float* Wp2   = (const float*)d_in[19];
    const float* bp2   = (const float*)d_in[20];
    const float* Wv1   = (const float*)d_in[21];
    const float* bv1   = (const float*)d_in[22];
    const float* Wv2   = (const float*)d_in[23];
    const float* bv2   = (const float*)d_in[24];
    float* out = (float*)d_out;
    char* base = (char*)d_ws;

    // ---- workspace layout (bytes) ----
    unsigned short* a1   = (unsigned short*)(base);             // 26,214,400
    unsigned short* a2   = (unsigned short*)(base + 26214432);  // 10,616,832
    unsigned short* W2p  = (unsigned short*)(base + 36831328);  // 65,536
    unsigned short* W3p  = (unsigned short*)(base + 36896864);  // 73,728
    unsigned short* Wfcp = (unsigned short*)(base + 36970592);  // 3,211,264
    unsigned short* Wihp = (unsigned short*)(base + 40181856);  // 1,048,576
    unsigned short* W1p  = (unsigned short*)(base + 41230432);  // 12,288
    unsigned int*   amax = (unsigned int*)(base + 41242752);    // 4 (+pad)
    signed char*    Wq   = (signed char*)(base + 41242784);     // 262,144
    unsigned short* a3   = (unsigned short*)(base);             // overlays dead a1
    unsigned short* feat = (unsigned short*)(base + 6422528);
    float* gx = (float*)(base + 7471104);

    hipMemsetAsync(amax, 0, 4, stream);
    k_amax<<<1024, 256, 0, stream>>>(Whh, amax);
    k_prep<<<9640, 256, 0, stream>>>(W2, W3, Wfc, Wih, W1, Whh, amax, W2p, W3p, Wfcp, Wihp, W1p, Wq);
    k_conv1<<<2048, 256, 0, stream>>>(image, W1p, b1, a1);
    k_conv2<<<512, 256, 0, stream>>>(a1, W2p, b2, a2);
    k_conv3<<<512, 256, 0, stream>>>(a2, W3p, b3, a3);
    k_fc<<<dim3(32, 8), 512, 0, stream>>>(a3, Wfcp, bfc, feat);
    k_gx<<<dim3(32, 16), 512, 0, stream>>>(feat, Wihp, Wih, bih, bhh, act, gx);
    k_lstm_all<<<32, 1024, 0, stream>>>(h0, c0, done, gx, Wq, amax,
                                        Wp1, bp1, Wp2, bp2, Wv1, bv1, Wv2, bv2, out);
}

// Round 11
// 396.164 us; speedup vs baseline: 1.2287x; 1.2287x over previous
//
#include <hip/hip_runtime.h>
#include <math.h>

typedef float  f4v __attribute__((ext_vector_type(4)));
typedef short  s8v __attribute__((ext_vector_type(8)));
typedef int    i4v __attribute__((ext_vector_type(4)));

__device__ __forceinline__ float sigm(float x) { return 1.f / (1.f + expf(-x)); }
__device__ __forceinline__ unsigned short f2bf(float f) {
    unsigned int u = __float_as_uint(f);
    return (unsigned short)((u + 0x7FFF + ((u >> 16) & 1)) >> 16);   // RTNE
}
// packed f32x2 -> bf16x2 in ONE VALU op (lo = first arg)
__device__ __forceinline__ unsigned int cvt2(float lo, float hi) {
    unsigned int r;
    asm("v_cvt_pk_bf16_f32 %0, %1, %2" : "=v"(r) : "v"(lo), "v"(hi));
    return r;
}
__device__ __forceinline__ s8v pack8(float4 a, float4 b) {
    union { unsigned int u[4]; s8v v; } r;
    r.u[0] = cvt2(a.x, a.y); r.u[1] = cvt2(a.z, a.w);
    r.u[2] = cvt2(b.x, b.y); r.u[3] = cvt2(b.z, b.w);
    return r.v;
}
// async global->LDS DMA, 16 B per lane; dest must be linear (base + lane*16)
__device__ __forceinline__ void gload16(const void* g, void* l) {
    __builtin_amdgcn_global_load_lds((const __attribute__((address_space(1))) void*)g,
                                     (__attribute__((address_space(3))) void*)l, 16, 0, 0);
}

// ---------------- amax over Whh (for i8 quantization scale) ----------------
__global__ __launch_bounds__(256) void k_amax(const float* __restrict__ Whh,
                                              unsigned int* __restrict__ amax_bits) {
    int i = blockIdx.x * 256 + threadIdx.x;          // grid 1024 -> 262144
    float v = fabsf(Whh[i]);
#pragma unroll
    for (int o = 1; o < 64; o <<= 1) v = fmaxf(v, __shfl_xor(v, o));
    if ((threadIdx.x & 63) == 0) atomicMax(amax_bits, __float_as_uint(v));
}

// ---------------- prep: pack weights ----------------
// W2p: [64co][k=(ky*4+kx)*32+ci]   (tap-major K, 32768 ush)
// W3p: [64co][k=(ky*3+kx)*64+ci]   (tap-major K, K=576, 36864 ush)
__global__ __launch_bounds__(256) void k_prep(const float* __restrict__ W2, const float* __restrict__ W3,
                                              const float* __restrict__ Wfc, const float* __restrict__ Wih,
                                              const float* __restrict__ W1, const float* __restrict__ Whh,
                                              const unsigned int* __restrict__ amax_bits,
                                              unsigned short* __restrict__ W2p, unsigned short* __restrict__ W3p,
                                              unsigned short* __restrict__ Wfcp, unsigned short* __restrict__ Wihp,
                                              unsigned short* __restrict__ W1p, signed char* __restrict__ Wq) {
    int i = blockIdx.x * 256 + threadIdx.x;
    if (i < 32768) {
        int co = i >> 9, k = i & 511, t = k >> 5, ci = k & 31, ky = t >> 2, kx = t & 3;
        W2p[i] = f2bf(W2[co * 512 + ci * 16 + ky * 4 + kx]);
    } else if (i < 69632) {
        int j = i - 32768;
        int co = j / 576, k = j - co * 576, t = k >> 6, ci = k & 63;
        int ky = t / 3, kx = t - ky * 3;
        W3p[j] = f2bf(W3[((co * 64 + ci) * 3 + ky) * 3 + kx]);
    } else if (i < 1675264) {
        int j = i - 69632;
        Wfcp[j] = f2bf(Wfc[j]);
    } else if (i < 2199552) {
        int j = i - 1675264;
        int n = j >> 9, k = j & 511;
        Wihp[j] = f2bf(Wih[n * 517 + k]);
    } else if (i < 2205696) {
        int j = i - 2199552;
        W1p[j] = f2bf(W1[j] * (1.f / 255.f));
    } else if (i < 2467840) {
        int j = i - 2205696;
        float amax = __uint_as_float(amax_bits[0]);
        float s = 127.f / amax;
        int qv = (int)rintf(Whh[j] * s);
        qv = qv > 127 ? 127 : (qv < -127 ? -127 : qv);
        Wq[j] = (signed char)qv;                     // [1024][256] natural
    }
}

// ---------------- conv1: DMA-staged fp32 half-image, grid 2048 x 256 thr (R7 best) ------
__global__ __launch_bounds__(256, 3) void k_conv1(const float* __restrict__ img,
                                                  const unsigned short* __restrict__ Bw,
                                                  const float* __restrict__ bias,
                                                  unsigned short* __restrict__ out) {
    __shared__ float sF[12096];                      // 48,384 B (max: 3*48*84 fp32)
    int tid = threadIdx.x;
    int lane = tid & 63, w = tid >> 6;               // 4 waves
    int l15 = lane & 15, q = lane >> 4;
    int bh = blockIdx.x & 1;
    int im = blockIdx.x >> 1;
    const int y0    = bh ? 40 : 0;                   // staged rows [y0, y0+ny)
    const int S     = bh ? 14784 : 16128;            // bytes per channel span (ny*336)
    const int fullc = bh ? 14 : 15;                  // full 1KB DMA chunks per channel
    const int tailg = bh ? 28 : 48;                  // 16B tail granules per channel
    const int t0    = bh ? 13 : 0;                   // first M-tile
    const int nt    = bh ? 12 : 13;                  // tiles in this block
    char* sFb = (char*)sF;
    const char* gimg = (const char*)(img + (size_t)im * 21168);
    // ---- stage: per channel, full 1KB wave-chunks via DMA; tail via registers ----
    for (int c = 0; c < 3; ++c) {
        const char* gb = gimg + c * 28224 + y0 * 336;
        char* lb = sFb + c * S;
        for (int j = w; j < fullc; j += 4) {
            int off = j * 1024 + lane * 16;
            gload16(gb + off, lb + off);
        }
        if (w == c && lane < tailg) {
            int off = fullc * 1024 + lane * 16;
            *(float4*)(lb + off) = *(const float4*)(gb + off);
        }
    }
    // ---- B fragments (L2-hot) + per-(ks,q) channel/row offsets ----
    const unsigned short* Bp0 = Bw + l15 * 192 + q * 8;
    const unsigned short* Bp1 = Bw + (16 + l15) * 192 + q * 8;
    s8v bf0[6], bf1[6];
#pragma unroll
    for (int ks = 0; ks < 6; ++ks) {
        bf0[ks] = *(const s8v*)(Bp0 + ks * 32);
        bf1[ks] = *(const s8v*)(Bp1 + ks * 32);
    }
    int koff[6];
#pragma unroll
    for (int ks = 0; ks < 6; ++ks) {
        int kq = ks * 4 + q;                         // k0/8
        int c = kq >> 3, ky = kq & 7;
        koff[ks] = c * S + ky * 336;
    }
    __syncthreads();                                 // drains DMA (vmcnt 0) + tail writes
    // ---- compute: wave w owns local tiles {w, w+4, w+8, w+12} ∩ [0,nt) ----
    f4v acc[4][2];
#pragma unroll
    for (int i = 0; i < 4; ++i) { acc[i][0] = (f4v){0.f,0.f,0.f,0.f}; acc[i][1] = (f4v){0.f,0.f,0.f,0.f}; }
#pragma unroll
    for (int tt = 0; tt < 4; ++tt) {
        int li = w + tt * 4;
        if (li < nt) {
            int p = (t0 + li) * 16 + l15;            // pixel index, < 400
            int oy = p / 20, ox = p - oy * 20;
            int tb = (oy * 4 - y0) * 336 + ox * 16;
#pragma unroll
            for (int ks = 0; ks < 6; ++ks) {
                float4 a0 = *(const float4*)(sFb + koff[ks] + tb);
                float4 a1 = *(const float4*)(sFb + koff[ks] + tb + 16);
                s8v ua = pack8(a0, a1);
                acc[tt][0] = __builtin_amdgcn_mfma_f32_16x16x32_bf16(ua, bf0[ks], acc[tt][0], 0, 0, 0);
                acc[tt][1] = __builtin_amdgcn_mfma_f32_16x16x32_bf16(ua, bf1[ks], acc[tt][1], 0, 0, 0);
            }
        }
    }
    __syncthreads();                                 // all image reads done -> alias LDS
    // ---- epilogue: bias+relu+pack into aliased LDS [32 n][212] shorts ----
    unsigned short* cS = (unsigned short*)sFb;
    float b0v = bias[l15], b1v = bias[16 + l15];
#pragma unroll
    for (int tt = 0; tt < 4; ++tt) {
        int li = w + tt * 4;
        if (li < nt) {
            int pc = li * 16 + q * 4;
#pragma unroll
            for (int r = 0; r < 4; r += 2) {
                float v0 = acc[tt][0][r] + b0v;     v0 = v0 > 0.f ? v0 : 0.f;
                float v1 = acc[tt][0][r + 1] + b0v; v1 = v1 > 0.f ? v1 : 0.f;
                *(unsigned int*)&cS[l15 * 212 + pc + r] = cvt2(v0, v1);
                float u0 = acc[tt][1][r] + b1v;     u0 = u0 > 0.f ? u0 : 0.f;
                float u1 = acc[tt][1][r + 1] + b1v; u1 = u1 > 0.f ? u1 : 0.f;
                *(unsigned int*)&cS[(16 + l15) * 212 + pc + r] = cvt2(u0, u1);
            }
        }
    }
    __syncthreads();
    // ---- coalesced store: out[(im*32+n)*400 + t0*16 + p_local] ----
    int hc = nt * 8;                                 // u32 per output row
    const unsigned int* cw = (const unsigned int*)cS;
    for (int n = w; n < 32; n += 4) {
        const unsigned int* crow = cw + n * 106;
        unsigned int* orow = (unsigned int*)(out + (im * 32 + n) * 400 + t0 * 16);
        for (int j = lane; j < hc; j += 64) orow[j] = crow[j];
    }
}

// ---------------- conv2: LDS-staged implicit GEMM, 2 images/block, grid 512 (R7) --------
__global__ __launch_bounds__(256, 2) void k_conv2(const unsigned short* __restrict__ A,
                                                  const unsigned short* __restrict__ Bw,
                                                  const float* __restrict__ bias,
                                                  unsigned short* __restrict__ out) {
    __shared__ unsigned short sA[800 * 32];    // 51200 B
    __shared__ unsigned short c2s[64][196];    // 25088 B
    int tid = threadIdx.x;
    int lane = tid & 63, w = tid >> 6;
    int l15 = lane & 15, q = lane >> 4;
    int img0 = blockIdx.x * 2;
    char* sAb = (char*)sA;
    const s8v* srcv = (const s8v*)(A + img0 * 12800);
    for (int wi = tid; wi < 3200; wi += 256) {
        s8v v = srcv[wi];
        int f = wi * 8;
        int im = f / 12800, r = f - im * 12800, ci = r / 400, p = r - ci * 400;
#pragma unroll
        for (int j = 0; j < 8; ++j) {
            int R = im * 400 + p + j;
            int Rl = (R >> 1) + (R & 1) * 400;
            int by = (Rl * 32 + ci) * 2 ^ ((Rl & 7) << 4);
            *(unsigned short*)(sAb + by) = (unsigned short)v[j];
        }
    }
    __syncthreads();
    int Rb[3];
#pragma unroll
    for (int mf = 0; mf < 3; ++mf) {
        int t = w * 3 + mf;
        int im = t / 6;
        int pp = (t - im * 6) * 16 + l15;
        int px = pp > 80 ? 80 : pp;
        int oy = px / 9, ox = px - oy * 9;
        Rb[mf] = im * 400 + oy * 40 + ox * 2;
    }
    const unsigned short* Bp0 = Bw + l15 * 512 + q * 8;
    const unsigned short* Bp1 = Bw + (16 + l15) * 512 + q * 8;
    const unsigned short* Bp2 = Bw + (32 + l15) * 512 + q * 8;
    const unsigned short* Bp3 = Bw + (48 + l15) * 512 + q * 8;
    f4v acc[3][4];
#pragma unroll
    for (int i = 0; i < 3; ++i)
#pragma unroll
        for (int j = 0; j < 4; ++j) acc[i][j] = (f4v){0.f, 0.f, 0.f, 0.f};
#pragma unroll
    for (int s = 0; s < 16; ++s) {
        const int ky = s >> 2, kx = s & 3;
        const int d = ky * 20 + kx;
        s8v a[3];
#pragma unroll
        for (int mf = 0; mf < 3; ++mf) {
            int R = Rb[mf] + d;
            int Rl = (R >> 1) + (R & 1) * 400;
            int by = (Rl * 64 + q * 16) ^ ((Rl & 7) << 4);
            a[mf] = *(const s8v*)(sAb + by);
        }
        s8v b0 = *(const s8v*)(Bp0 + s * 32);
        s8v b1 = *(const s8v*)(Bp1 + s * 32);
        s8v b2 = *(const s8v*)(Bp2 + s * 32);
        s8v b3 = *(const s8v*)(Bp3 + s * 32);
#pragma unroll
        for (int mf = 0; mf < 3; ++mf) {
            acc[mf][0] = __builtin_amdgcn_mfma_f32_16x16x32_bf16(a[mf], b0, acc[mf][0], 0, 0, 0);
            acc[mf][1] = __builtin_amdgcn_mfma_f32_16x16x32_bf16(a[mf], b1, acc[mf][1], 0, 0, 0);
            acc[mf][2] = __builtin_amdgcn_mfma_f32_16x16x32_bf16(a[mf], b2, acc[mf][2], 0, 0, 0);
            acc[mf][3] = __builtin_amdgcn_mfma_f32_16x16x32_bf16(a[mf], b3, acc[mf][3], 0, 0, 0);
        }
    }
#pragma unroll
    for (int nf = 0; nf < 4; ++nf) {
        int co = nf * 16 + l15;
        float b = bias[co];
#pragma unroll
        for (int mf = 0; mf < 3; ++mf) {
            int rr = (w * 3 + mf) * 16 + q * 4;
#pragma unroll
            for (int r = 0; r < 4; r += 2) {
                float v0 = acc[mf][nf][r] + b;     v0 = v0 > 0.f ? v0 : 0.f;
                float v1 = acc[mf][nf][r + 1] + b; v1 = v1 > 0.f ? v1 : 0.f;
                *(unsigned int*)&c2s[co][rr + r] = cvt2(v0, v1);
            }
        }
    }
    __syncthreads();
    for (int idx = tid; idx < 10368; idx += 256) {
        int im = idx / 5184, r2 = idx - im * 5184, co = r2 / 81, p = r2 - co * 81;
        out[(img0 + im) * 5184 + r2] = c2s[co][im * 96 + p];
    }
}

// ---------------- conv3: LDS-staged implicit GEMM, 2 images/block, grid 512 (R7) --------
__global__ __launch_bounds__(256, 2) void k_conv3(const unsigned short* __restrict__ A,
                                                  const unsigned short* __restrict__ Bw,
                                                  const float* __restrict__ bias,
                                                  unsigned short* __restrict__ out) {
    __shared__ unsigned short sA[162 * 64];    // 20736 B
    __shared__ unsigned short c3s[64][132];    // 16896 B
    int tid = threadIdx.x;
    int lane = tid & 63, w = tid >> 6;
    int l15 = lane & 15, q = lane >> 4;
    int img0 = blockIdx.x * 2;
    char* sAb = (char*)sA;
    const s8v* srcv = (const s8v*)(A + img0 * 5184);
    for (int wi = tid; wi < 1296; wi += 256) {
        s8v v = srcv[wi];
        int f = wi * 8;
#pragma unroll
        for (int j = 0; j < 8; ++j) {
            int fe = f + j;
            int im = fe / 5184, r = fe - im * 5184, ci = r / 81, p = r - ci * 81;
            int R = im * 81 + p;
            int by = (R * 64 + ci) * 2 ^ ((R & 7) << 4);
            *(unsigned short*)(sAb + by) = (unsigned short)v[j];
        }
    }
    __syncthreads();
    int Rb[2];
#pragma unroll
    for (int mf = 0; mf < 2; ++mf) {
        int t = w * 2 + mf;
        int im = t >> 2;
        int pp = (t & 3) * 16 + l15;
        int px = pp > 48 ? 48 : pp;
        int oy = px / 7, ox = px - oy * 7;
        Rb[mf] = im * 81 + oy * 9 + ox;
    }
    const unsigned short* Bp0 = Bw + l15 * 576 + q * 8;
    const unsigned short* Bp1 = Bw + (16 + l15) * 576 + q * 8;
    const unsigned short* Bp2 = Bw + (32 + l15) * 576 + q * 8;
    const unsigned short* Bp3 = Bw + (48 + l15) * 576 + q * 8;
    f4v acc[2][4];
#pragma unroll
    for (int i = 0; i < 2; ++i)
#pragma unroll
        for (int j = 0; j < 4; ++j) acc[i][j] = (f4v){0.f, 0.f, 0.f, 0.f};
#pragma unroll
    for (int s = 0; s < 18; ++s) {
        const int tap = s >> 1, cb2 = (s & 1) * 64;
        const int ky = tap / 3, kx = tap - ky * 3;
        const int d = ky * 9 + kx;
        s8v a0, a1;
        {
            int R = Rb[0] + d;
            int by = (R * 128 + cb2 + q * 16) ^ ((R & 7) << 4);
            a0 = *(const s8v*)(sAb + by);
        }
        {
            int R = Rb[1] + d;
            int by = (R * 128 + cb2 + q * 16) ^ ((R & 7) << 4);
            a1 = *(const s8v*)(sAb + by);
        }
        s8v b0 = *(const s8v*)(Bp0 + s * 32);
        s8v b1 = *(const s8v*)(Bp1 + s * 32);
        s8v b2 = *(const s8v*)(Bp2 + s * 32);
        s8v b3 = *(const s8v*)(Bp3 + s * 32);
        acc[0][0] = __builtin_amdgcn_mfma_f32_16x16x32_bf16(a0, b0, acc[0][0], 0, 0, 0);
        acc[0][1] = __builtin_amdgcn_mfma_f32_16x16x32_bf16(a0, b1, acc[0][1], 0, 0, 0);
        acc[0][2] = __builtin_amdgcn_mfma_f32_16x16x32_bf16(a0, b2, acc[0][2], 0, 0, 0);
        acc[0][3] = __builtin_amdgcn_mfma_f32_16x16x32_bf16(a0, b3, acc[0][3], 0, 0, 0);
        acc[1][0] = __builtin_amdgcn_mfma_f32_16x16x32_bf16(a1, b0, acc[1][0], 0, 0, 0);
        acc[1][1] = __builtin_amdgcn_mfma_f32_16x16x32_bf16(a1, b1, acc[1][1], 0, 0, 0);
        acc[1][2] = __builtin_amdgcn_mfma_f32_16x16x32_bf16(a1, b2, acc[1][2], 0, 0, 0);
        acc[1][3] = __builtin_amdgcn_mfma_f32_16x16x32_bf16(a1, b3, acc[1][3], 0, 0, 0);
    }
#pragma unroll
    for (int nf = 0; nf < 4; ++nf) {
        int co = nf * 16 + l15;
        float b = bias[co];
#pragma unroll
        for (int mf = 0; mf < 2; ++mf) {
            int rr = (w * 2 + mf) * 16 + q * 4;
#pragma unroll
            for (int r = 0; r < 4; r += 2) {
                float v0 = acc[mf][nf][r] + b;     v0 = v0 > 0.f ? v0 : 0.f;
                float v1 = acc[mf][nf][r + 1] + b; v1 = v1 > 0.f ? v1 : 0.f;
                *(unsigned int*)&c3s[co][rr + r] = cvt2(v0, v1);
            }
        }
    }
    __syncthreads();
    for (int idx = tid; idx < 6272; idx += 256) {
        int im = idx / 3136, r2 = idx - im * 3136, co = r2 / 49, p = r2 - co * 49;
        out[(img0 + im) * 3136 + r2] = c3s[co][im * 64 + p];
    }
}

// ---------------- FC: LDS-staged GEMM, 16x64 tile, 256 thr, grid (64,8) -----------------
// M-split 32->16 doubles grid to 512 blocks -> 2 blocks/CU (was 1): barrier drains of the
// two resident blocks interleave. Same swizzle/fragment math as the proven 32x64 version.
__global__ __launch_bounds__(256) void k_fc(const unsigned short* __restrict__ A,
                                            const unsigned short* __restrict__ Bw,
                                            const float* __restrict__ bias,
                                            unsigned short* __restrict__ out) {
    __shared__ unsigned short sA[16 * 128];          // 4 KB
    __shared__ unsigned short sB[64 * 128];          // 16 KB
    int tid = threadIdx.x;
    int lane = tid & 63, w = tid >> 6;               // 4 waves
    int l15 = lane & 15, q = lane >> 4;
    int m0 = blockIdx.x * 16, n0 = blockIdx.y * 64;
    char* sAb = (char*)sA; char* sBb = (char*)sB;
    int ar = l15;                                    // A fragment row (16 rows)
    int br = w * 16 + l15;                           // B fragment row (wave = n-quarter)
    f4v acc = (f4v){0.f, 0.f, 0.f, 0.f};
    for (int ks = 0; ks < 25; ++ks) {
        int kb = ks * 128;
        if (ks < 24) {
            {   // A: 256 granules (16 rows x 16), one per thread
                int row = tid >> 4, kg = tid & 15;
                s8v v = *(const s8v*)(A + (m0 + row) * 3136 + kb + kg * 8);
                int by = (row * 256 + kg * 16) ^ ((row & 7) << 4);
                *(s8v*)(sAb + by) = v;
            }
#pragma unroll
            for (int h = 0; h < 4; ++h) {            // B: 1024 granules (64 rows x 16)
                int g = tid + h * 256;
                int row = g >> 4, kg = g & 15;
                s8v v = *(const s8v*)(Bw + (n0 + row) * 3136 + kb + kg * 8);
                int by = (row * 256 + kg * 16) ^ ((row & 7) << 4);
                *(s8v*)(sBb + by) = v;
            }
        } else {                                     // tail: bk = 64 (8 granules/row)
            if (tid < 128) {                         // A: 16 rows x 8
                int row = tid >> 3, kg = tid & 7;
                s8v v = *(const s8v*)(A + (m0 + row) * 3136 + kb + kg * 8);
                int by = (row * 256 + kg * 16) ^ ((row & 7) << 4);
                *(s8v*)(sAb + by) = v;
            }
#pragma unroll
            for (int h = 0; h < 2; ++h) {            // B: 64 rows x 8 = 512
                int g = tid + h * 256;
                int row = g >> 3, kg = g & 7;
                s8v v = *(const s8v*)(Bw + (n0 + row) * 3136 + kb + kg * 8);
                int by = (row * 256 + kg * 16) ^ ((row & 7) << 4);
                *(s8v*)(sBb + by) = v;
            }
        }
        __syncthreads();
        int nkc = (ks < 24) ? 4 : 2;
        for (int kc = 0; kc < nkc; ++kc) {
            int abz = (ar * 256 + kc * 64 + q * 16) ^ ((ar & 7) << 4);
            int bbz = (br * 256 + kc * 64 + q * 16) ^ ((br & 7) << 4);
            s8v av = *(const s8v*)(sAb + abz);
            s8v bv = *(const s8v*)(sBb + bbz);
            acc = __builtin_amdgcn_mfma_f32_16x16x32_bf16(av, bv, acc, 0, 0, 0);
        }
        __syncthreads();
    }
    int n = n0 + w * 16 + l15;
    float bi = bias[n];
#pragma unroll
    for (int r = 0; r < 4; ++r) {
        int m = m0 + q * 4 + r;
        float v = acc[r] + bi; v = v > 0.f ? v : 0.f;
        out[m * 512 + n] = f2bf(v);
    }
}

// ---------------- gx: LDS-staged GEMM, 32x64 tile, 512 thr, grid (32,16) (R7) -----------
__global__ __launch_bounds__(512) void k_gx(const unsigned short* __restrict__ A,
                                            const unsigned short* __restrict__ Bw,
                                            const float* __restrict__ Wih,
                                            const float* __restrict__ bih,
                                            const float* __restrict__ bhh,
                                            const int* __restrict__ act,
                                            float* __restrict__ out) {
    __shared__ unsigned short sA[32 * 128];          // 8 KB
    __shared__ unsigned short sB[64 * 128];          // 16 KB
    int tid = threadIdx.x;
    int lane = tid & 63, w = tid >> 6;
    int l15 = lane & 15, q = lane >> 4;
    int m0 = blockIdx.x * 32, n0 = blockIdx.y * 64;
    int mh = w & 1, nh = w >> 1;
    char* sAb = (char*)sA; char* sBb = (char*)sB;
    int ar = mh * 16 + l15;
    int br = nh * 16 + l15;
    f4v acc = (f4v){0.f, 0.f, 0.f, 0.f};
#pragma unroll
    for (int ks = 0; ks < 4; ++ks) {
        int kb = ks * 128;
        {
            int row = tid >> 4, kg = tid & 15;
            s8v v = *(const s8v*)(A + (m0 + row) * 512 + kb + kg * 8);
            int by = (row * 256 + kg * 16) ^ ((row & 7) << 4);
            *(s8v*)(sAb + by) = v;
        }
#pragma unroll
        for (int h = 0; h < 2; ++h) {
            int g = tid + h * 512;
            int row = g >> 4, kg = g & 15;
            s8v v = *(const s8v*)(Bw + (n0 + row) * 512 + kb + kg * 8);
            int by = (row * 256 + kg * 16) ^ ((row & 7) << 4);
            *(s8v*)(sBb + by) = v;
        }
        __syncthreads();
#pragma unroll
        for (int kc = 0; kc < 4; ++kc) {
            int abz = (ar * 256 + kc * 64 + q * 16) ^ ((ar & 7) << 4);
            int bbz = (br * 256 + kc * 64 + q * 16) ^ ((br & 7) << 4);
            s8v av = *(const s8v*)(sAb + abz);
            s8v bv = *(const s8v*)(sBb + bbz);
            acc = __builtin_amdgcn_mfma_f32_16x16x32_bf16(av, bv, acc, 0, 0, 0);
        }
        __syncthreads();
    }
    int n = n0 + nh * 16 + l15;
    float cbias = bih[n] + bhh[n];
#pragma unroll
    for (int r = 0; r < 4; ++r) {
        int m = m0 + mh * 16 + q * 4 + r;
        int a = act[m];
        out[m * 1024 + n] = acc[r] + Wih[n * 517 + 512 + a] + cbias;
    }
}

// ---------------- fused LSTM, env-split: 32 wgs x 1 env (R7, un-fused) ------------------
__global__ __launch_bounds__(1024) void k_lstm_all(const float* __restrict__ h0,
                                                   const float* __restrict__ c0,
                                                   const float* __restrict__ done,
                                                   const float* __restrict__ gx,
                                                   const signed char* __restrict__ Wq,
                                                   const unsigned int* __restrict__ amax_bits,
                                                   float* __restrict__ hs,
                                                   float* __restrict__ cb) {
    int b = blockIdx.x;
    int tid = threadIdx.x;
    int w = tid >> 6, lane = tid & 63;
    int l15 = lane & 15, q = lane >> 4;
    __shared__ float gbuf[1024];
    __shared__ float cst[256];
    __shared__ signed char hA[4][64][16];            // A-operand layout, only m=0 rows live

    i4v wfr[4][4];
    const signed char* wb = Wq + (w * 64 + l15) * 256 + q * 16;
#pragma unroll
    for (int s = 0; s < 4; ++s)
#pragma unroll
        for (int kf = 0; kf < 4; ++kf)
            wfr[s][kf] = *(const i4v*)(wb + s * 16 * 256 + kf * 64);
    float sw = __uint_as_float(amax_bits[0]) * (1.f / (127.f * 127.f));

    ((int*)hA)[tid] = 0;                             // zero all (dead rows stay 0)
    __syncthreads();
    if (tid < 256) {
        int u = tid;
        cst[u] = c0[b * 256 + u];
        float m0v = 1.f - done[b];
        float hv = h0[b * 256 + u] * m0v;
        hv = hv > 1.f ? 1.f : (hv < -1.f ? -1.f : hv);
        hA[u >> 6][((u >> 4) & 3) * 16][u & 15] = (signed char)(int)rintf(hv * 127.f);
    }
    __syncthreads();

    for (int t = 0; t < 32; ++t) {
        float gxi = 0.f, gxf = 0.f, gxg = 0.f, gxo = 0.f, dcur = 0.f, dnxt = 0.f;
        if (tid < 256) {
            const float* gr = gx + (t * 32 + b) * 1024;
            gxi = gr[tid]; gxf = gr[256 + tid]; gxg = gr[512 + tid]; gxo = gr[768 + tid];
            dcur = done[t * 32 + b];
            dnxt = (t < 31) ? done[(t + 1) * 32 + b] : 1.f;
        }
        i4v acc[4];
#pragma unroll
        for (int s = 0; s < 4; ++s) acc[s] = (i4v){0, 0, 0, 0};
#pragma unroll
        for (int kf = 0; kf < 4; ++kf) {
            i4v a = *(const i4v*)&hA[kf][lane][0];
#pragma unroll
            for (int s = 0; s < 4; ++s)
                acc[s] = __builtin_amdgcn_mfma_i32_16x16x64_i8(a, wfr[s][kf], acc[s], 0, 0, 0);
        }
        if (q == 0) {                                // row 0 of C lives in reg 0 of lanes 0..15
#pragma unroll
            for (int s = 0; s < 4; ++s)
                gbuf[w * 64 + s * 16 + l15] = (float)acc[s][0];
        }
        __syncthreads();
        if (tid < 256) {
            int u = tid;
            float gi = gbuf[u] * sw + gxi;
            float gf = gbuf[256 + u] * sw + gxf;
            float gg = gbuf[512 + u] * sw + gxg;
            float go = gbuf[768 + u] * sw + gxo;
            float cm = cst[u] * (1.f - dcur);
            float cn = sigm(gf) * cm + sigm(gi) * tanhf(gg);
            float hn = sigm(go) * tanhf(cn);
            cst[u] = cn;
            hs[t * 8192 + b * 256 + u] = hn;
            float hv = hn * (1.f - dnxt);            // |h|<1; done in {0,1} -> exact
            hA[u >> 6][((u >> 4) & 3) * 16][u & 15] = (signed char)(int)rintf(hv * 127.f);
        }
        __syncthreads();
    }
    if (tid < 256) cb[b * 256 + tid] = cst[tid];
}

// ---------------- heads (fp32, R7) ----------------
__global__ __launch_bounds__(256) void k_heads(const float* __restrict__ hs,
                                               const float* __restrict__ cb,
                                               const float* __restrict__ Wp1, const float* __restrict__ bp1,
                                               const float* __restrict__ Wp2, const float* __restrict__ bp2,
                                               const float* __restrict__ Wv1, const float* __restrict__ bv1,
                                               const float* __restrict__ Wv2, const float* __restrict__ bv2,
                                               float* __restrict__ out) {
    int lane = threadIdx.x & 63;
    int m = blockIdx.x * 4 + (threadIdx.x >> 6);   // 0..1023
    const float4* hv = (const float4*)(hs + m * 256);
    const float4* wp = (const float4*)(Wp1 + lane * 256);
    const float4* wq = (const float4*)(Wv1 + lane * 256);
    float ap = 0.f, av = 0.f;
#pragma unroll 8
    for (int k = 0; k < 64; ++k) {
        float4 h4 = hv[k];
        float4 p4 = wp[k];
        float4 q4 = wq[k];
        ap += h4.x * p4.x + h4.y * p4.y + h4.z * p4.z + h4.w * p4.w;
        av += h4.x * q4.x + h4.y * q4.y + h4.z * q4.z + h4.w * q4.w;
    }
    float hp = tanhf(ap + bp1[lane]);
    float hq = tanhf(av + bv1[lane]);
#pragma unroll
    for (int j = 0; j < 5; ++j) {
        float s = hp * Wp2[j * 64 + lane];
        s += __shfl_xor(s, 1); s += __shfl_xor(s, 2); s += __shfl_xor(s, 4);
        s += __shfl_xor(s, 8); s += __shfl_xor(s, 16); s += __shfl_xor(s, 32);
        if (lane == 0) out[m * 5 + j] = s + bp2[j];
    }
    float s = hq * Wv2[lane];
    s += __shfl_xor(s, 1); s += __shfl_xor(s, 2); s += __shfl_xor(s, 4);
    s += __shfl_xor(s, 8); s += __shfl_xor(s, 16); s += __shfl_xor(s, 32);
    if (lane == 0) out[5120 + m] = s + bv2[0];

    int g = blockIdx.x * 256 + threadIdx.x;
    if (g < 8192) {
        out[6144 + g] = hs[31 * 8192 + g];          // hT
        out[6144 + 8192 + g] = cb[g];               // cT
    }
}

extern "C" void kernel_launch(void* const* d_in, const int* in_sizes, int n_in,
                              void* d_out, int out_size, void* d_ws, size_t ws_size,
                              hipStream_t stream) {
    const float* image = (const float*)d_in[0];
    const int*   act   = (const int*)d_in[1];
    const float* done  = (const float*)d_in[2];
    const float* h0    = (const float*)d_in[3];
    const float* c0    = (const float*)d_in[4];
    const float* W1    = (const float*)d_in[5];
    const float* b1    = (const float*)d_in[6];
    const float* W2    = (const float*)d_in[7];
    const float* b2    = (const float*)d_in[8];
    const float* W3    = (const float*)d_in[9];
    const float* b3    = (const float*)d_in[10];
    const float* Wfc   = (const float*)d_in[11];
    const float* bfc   = (const float*)d_in[12];
    const float* Wih   = (const float*)d_in[13];
    const float* Whh   = (const float*)d_in[14];
    const float* bih   = (const float*)d_in[15];
    const float* bhh   = (const float*)d_in[16];
    const float* Wp1   = (const float*)d_in[17];
    const float* bp1   = (const float*)d_in[18];
    const float* Wp2   = (const float*)d_in[19];
    const float* bp2   = (const float*)d_in[20];
    const float* Wv1   = (const float*)d_in[21];
    const float* bv1   = (const float*)d_in[22];
    const float* Wv2   = (const float*)d_in[23];
    const float* bv2   = (const float*)d_in[24];
    float* out = (float*)d_out;
    char* base = (char*)d_ws;

    // ---- workspace layout (bytes) ----
    unsigned short* a1   = (unsigned short*)(base);             // 26,214,400
    unsigned short* a2   = (unsigned short*)(base + 26214432);  // 10,616,832
    unsigned short* W2p  = (unsigned short*)(base + 36831328);  // 65,536
    unsigned short* W3p  = (unsigned short*)(base + 36896864);  // 73,728
    unsigned short* Wfcp = (unsigned short*)(base + 36970592);  // 3,211,264
    unsigned short* Wihp = (unsigned short*)(base + 40181856);  // 1,048,576
    unsigned short* W1p  = (unsigned short*)(base + 41230432);  // 12,288
    unsigned int*   amax = (unsigned int*)(base + 41242752);    // 4 (+pad)
    signed char*    Wq   = (signed char*)(base + 41242784);     // 262,144
    unsigned short* a3   = (unsigned short*)(base);             // overlays dead a1
    unsigned short* feat = (unsigned short*)(base + 6422528);
    float* gx = (float*)(base + 7471104);
    float* hs = (float*)(base + 11665408);
    float* cb = (float*)(base + 12713984);

    hipMemsetAsync(amax, 0, 4, stream);
    k_amax<<<1024, 256, 0, stream>>>(Whh, amax);
    k_prep<<<9640, 256, 0, stream>>>(W2, W3, Wfc, Wih, W1, Whh, amax, W2p, W3p, Wfcp, Wihp, W1p, Wq);
    k_conv1<<<2048, 256, 0, stream>>>(image, W1p, b1, a1);
    k_conv2<<<512, 256, 0, stream>>>(a1, W2p, b2, a2);
    k_conv3<<<512, 256, 0, stream>>>(a2, W3p, b3, a3);
    k_fc<<<dim3(64, 8), 256, 0, stream>>>(a3, Wfcp, bfc, feat);
    k_gx<<<dim3(32, 16), 512, 0, stream>>>(feat, Wihp, Wih, bih, bhh, act, gx);
    k_lstm_all<<<32, 1024, 0, stream>>>(h0, c0, done, gx, Wq, amax, hs, cb);
    k_heads<<<256, 256, 0, stream>>>(hs, cb, Wp1, bp1, Wp2, bp2, Wv1, bv1, Wv2, bv2, out);
}